// Round 16
// baseline (224.838 us; speedup 1.0000x reference)
//
#include <hip/hip_runtime.h>
#include <hip/hip_bf16.h>

#define NN 50000
#define EE 800000
#define INDIM 128
#define HIDC 16
#define NHEAD 8
#define COARSE 196          // ceil(NN/256)
#define EPB 2048            // edges per block in partition pass A
#define CAPR 6144           // fixed region stride per coarse bin (avg cnt ~4082)
#define CAPB 8192           // partB LDS stage capacity (>= CAPR)
#define CVT_BLKS 37         // ceil((256*128/4 + 32*128/4 + 144)/256)
#define HSTRIDE 136         // LDS row stride (ushort) for h_act tile: 8-aligned

typedef __attribute__((ext_vector_type(8))) short bf16x8;
typedef __attribute__((ext_vector_type(4))) float f32x4;

__device__ __forceinline__ float bf2f(unsigned short u) {
    union { float f; unsigned int i; } v; v.i = ((unsigned int)u) << 16; return v.f;
}
__device__ __forceinline__ unsigned short f2bf(float f) {
    union { float f; unsigned int i; } v; v.f = f;
    unsigned int r = v.i + 0x7FFFu + ((v.i >> 16) & 1u);
    return (unsigned short)(r >> 16);
}

// ---------------------------------------------------------------------------
// K_PREP: blocks [0, CVT_BLKS): weight bf16 conversion + BN constants.
//         blocks [CVT_BLKS, ...): partition pass A (independent of cvt).
// ---------------------------------------------------------------------------
__global__ __launch_bounds__(256) void k_prep(
    const float* __restrict__ w0, const float* __restrict__ skip0,
    const float* __restrict__ w1, const float* __restrict__ skip1,
    const float* __restrict__ b0, const float* __restrict__ g0,
    const float* __restrict__ bb0, const float* __restrict__ m0,
    const float* __restrict__ v0,
    const float* __restrict__ b1, const float* __restrict__ g1,
    const float* __restrict__ bb1, const float* __restrict__ m1,
    const float* __restrict__ v1,
    unsigned int* __restrict__ wb2, unsigned int* __restrict__ wb1_2,
    float2* __restrict__ acb0, float2* __restrict__ acb1,
    const int* __restrict__ ei, int* __restrict__ ccur0,
    unsigned int* __restrict__ pairs)
{
    if (blockIdx.x < CVT_BLKS) {
        const long NW = 256 * 128 / 4;           // w0|skip0 float4 blocks
        const long NW1 = 32 * 128 / 4;           // w1|skip1
        long i = (long)blockIdx.x * 256 + threadIdx.x;
        if (i < NW) {
            const float4* src = (i < 128 * 128 / 4) ? ((const float4*)w0 + i)
                                                    : ((const float4*)skip0 + (i - 128 * 128 / 4));
            float4 v = *src;
            wb2[i * 2]     = (unsigned int)f2bf(v.x) | ((unsigned int)f2bf(v.y) << 16);
            wb2[i * 2 + 1] = (unsigned int)f2bf(v.z) | ((unsigned int)f2bf(v.w) << 16);
        } else if (i < NW + NW1) {
            long j = i - NW;
            const float4* src = (j < 16 * 128 / 4) ? ((const float4*)w1 + j)
                                                   : ((const float4*)skip1 + (j - 16 * 128 / 4));
            float4 v = *src;
            wb1_2[j * 2]     = (unsigned int)f2bf(v.x) | ((unsigned int)f2bf(v.y) << 16);
            wb1_2[j * 2 + 1] = (unsigned int)f2bf(v.z) | ((unsigned int)f2bf(v.w) << 16);
        } else if (i < NW + NW1 + 128) {
            int c = (int)(i - NW - NW1);
            float A = g0[c] * rsqrtf(v0[c] + 1e-5f);
            acb0[c] = make_float2(A, (b0[c] - m0[c]) * A + bb0[c]);
        } else if (i < NW + NW1 + 128 + 16) {
            int c = (int)(i - NW - NW1 - 128);
            float A = g1[c] * rsqrtf(v1[c] + 1e-5f);
            acb1[c] = make_float2(A, (b1[c] - m1[c]) * A + bb1[c]);
        }
        return;
    }

    // ---- partition pass A ----
    __shared__ int bcnt[256];
    __shared__ int lofs[256];
    __shared__ int gofs[256];
    __shared__ unsigned int stage[EPB];
    __shared__ int gpos[EPB];
    const int t = threadIdx.x;
    const int e0 = (blockIdx.x - CVT_BLKS) * EPB;

    bcnt[t] = 0;
    __syncthreads();

    int mybin[8], myrank[8];
    unsigned int mypair[8];
    #pragma unroll
    for (int k = 0; k < 8; k++) {
        int e = e0 + k * 256 + t;
        mybin[k] = -1;
        if (e < EE) {
            int s = ei[e], d = ei[EE + e];
            int b = d >> 8;
            myrank[k] = atomicAdd(&bcnt[b], 1);
            mybin[k] = b;
            mypair[k] = ((unsigned)d << 16) | (unsigned)s;
        }
    }
    __syncthreads();

    int v = bcnt[t];
    lofs[t] = v;
    __syncthreads();
    for (int off = 1; off < 256; off <<= 1) {
        int u = (t >= off) ? lofs[t - off] : 0;
        __syncthreads();
        lofs[t] += u;
        __syncthreads();
    }
    if (t < COARSE && v > 0)
        gofs[t] = t * CAPR + atomicAdd(&ccur0[t], v);
    __syncthreads();

    #pragma unroll
    for (int k = 0; k < 8; k++) {
        int b = mybin[k];
        if (b >= 0) {
            int slot = (lofs[b] - bcnt[b]) + myrank[k];
            stage[slot] = mypair[k];
            gpos[slot]  = gofs[b] + myrank[k];
        }
    }
    __syncthreads();

    const int total = lofs[255];
    for (int i = t; i < total; i += 256)
        pairs[gpos[i]] = stage[i];
}

// ---------------------------------------------------------------------------
// K_MID: blocks [0, COARSE): partition pass B (LDS counting-sort by dst).
//        blocks [COARSE, ...): gemm0 (needs only wb from k_prep).
// ---------------------------------------------------------------------------
__global__ __launch_bounds__(256) void k_mid(
    const unsigned int* __restrict__ pairs, const int* __restrict__ ccur0,
    unsigned short* __restrict__ srcidx, int* __restrict__ rowbeg,
    int* __restrict__ deg,
    const float* __restrict__ x, const unsigned short* __restrict__ wb,
    const float* __restrict__ asrc0, const float* __restrict__ adst0,
    unsigned char* __restrict__ h0f, unsigned short* __restrict__ s0b,
    float* __restrict__ a_src0, float* __restrict__ a_dst0)
{
    __shared__ int fcnt[256], fofs[256], fcur[256];
    __shared__ unsigned short stage[CAPB];

    if (blockIdx.x < COARSE) {
        const int b = blockIdx.x, t = threadIdx.x;
        const int beg = b * CAPR;
        int cnt = ccur0[b];
        if (cnt > CAPR) cnt = CAPR;   // safety clamp

        fcnt[t] = 0;
        __syncthreads();
        for (int i = t; i < cnt; i += 256) {
            unsigned int d = pairs[beg + i] >> 16;
            atomicAdd(&fcnt[d & 255], 1);
        }
        __syncthreads();

        int v = fcnt[t];
        fofs[t] = v;
        __syncthreads();
        for (int off = 1; off < 256; off <<= 1) {
            int u = (t >= off) ? fofs[t - off] : 0;
            __syncthreads();
            fofs[t] += u;
            __syncthreads();
        }
        int ex = fofs[t] - v;
        int node = b * 256 + t;
        if (node < NN) { rowbeg[node] = beg + ex; deg[node] = v; }
        fcur[t] = ex;
        __syncthreads();

        for (int i = t; i < cnt; i += 256) {
            unsigned int p = pairs[beg + i];
            unsigned int d = p >> 16;
            int slot = atomicAdd(&fcur[d & 255], 1);
            stage[slot] = (unsigned short)(p & 0xFFFFu);
        }
        __syncthreads();
        for (int i = t; i < cnt; i += 256)
            srcidx[beg + i] = stage[i];
        return;
    }

    // ---- gemm0 ----
    const int bid = blockIdx.x - COARSE;
    const int wave = threadIdx.x >> 6;
    const int lane = threadIdx.x & 63;
    const int lrow = lane & 15;
    const int quad = lane >> 4;
    const int rowbase = bid * 32;

    // A fragments for 2 row-subtiles, from fp32 x, converted in-register
    bf16x8 afrag[2][4];
    #pragma unroll
    for (int sub = 0; sub < 2; sub++) {
        const int row = min(rowbase + sub * 16 + lrow, NN - 1);
        const float* xr = x + (long)row * 128;
        #pragma unroll
        for (int ki = 0; ki < 4; ki++) {
            float4 a = *(const float4*)(xr + ki * 32 + quad * 8);
            float4 b = *(const float4*)(xr + ki * 32 + quad * 8 + 4);
            bf16x8 f;
            f[0] = (short)f2bf(a.x); f[1] = (short)f2bf(a.y);
            f[2] = (short)f2bf(a.z); f[3] = (short)f2bf(a.w);
            f[4] = (short)f2bf(b.x); f[5] = (short)f2bf(b.y);
            f[6] = (short)f2bf(b.z); f[7] = (short)f2bf(b.w);
            afrag[sub][ki] = f;
        }
    }

    #pragma unroll
    for (int t = 0; t < 4; t++) {
        const int jg = wave * 64 + t * 16 + lrow;
        bf16x8 bfrag[4];
        #pragma unroll
        for (int ki = 0; ki < 4; ki++)
            bfrag[ki] = *(const bf16x8*)(wb + (long)jg * 128 + ki * 32 + quad * 8);
        float4 asv = {0.f, 0.f, 0.f, 0.f}, adv = {0.f, 0.f, 0.f, 0.f};
        if (wave < 2) {
            const int cb = wave * 64 + t * 16 + quad * 4;
            asv = *(const float4*)(asrc0 + cb);
            adv = *(const float4*)(adst0 + cb);
        }
        #pragma unroll
        for (int sub = 0; sub < 2; sub++) {
            f32x4 acc = (f32x4){0.f, 0.f, 0.f, 0.f};
            // swapped operands: D^T -> col(lane&15)=node, row(quad*4+r)=channel
            #pragma unroll
            for (int ki = 0; ki < 4; ki++)
                acc = __builtin_amdgcn_mfma_f32_16x16x32_bf16(bfrag[ki], afrag[sub][ki], acc, 0, 0, 0);

            const int node = rowbase + sub * 16 + lrow;
            if (node < NN) {
                if (wave < 2) {
                    const int cb = wave * 64 + t * 16 + quad * 4;
                    unsigned int u = __builtin_amdgcn_cvt_pk_fp8_f32(acc[0], acc[1], 0u, 0);
                    u = __builtin_amdgcn_cvt_pk_fp8_f32(acc[2], acc[3], u, 1);
                    *(unsigned int*)(h0f + (long)node * 128 + cb) = u;
                    float ps = acc[0] * asv.x + acc[1] * asv.y + acc[2] * asv.z + acc[3] * asv.w;
                    float pd = acc[0] * adv.x + acc[1] * adv.y + acc[2] * adv.z + acc[3] * adv.w;
                    ps += __shfl_xor(ps, 16); ps += __shfl_xor(ps, 32);
                    pd += __shfl_xor(pd, 16); pd += __shfl_xor(pd, 32);
                    if (quad == 0) {
                        const int h = wave * 4 + t;
                        a_src0[(long)node * 8 + h] = ps;
                        a_dst0[(long)node * 8 + h] = pd;
                    }
                } else {
                    const int cb = (wave - 2) * 64 + t * 16 + quad * 4;
                    uint2 u;
                    u.x = (unsigned int)f2bf(acc[0]) | ((unsigned int)f2bf(acc[1]) << 16);
                    u.y = (unsigned int)f2bf(acc[2]) | ((unsigned int)f2bf(acc[3]) << 16);
                    *(uint2*)(s0b + (long)node * 128 + cb) = u;
                }
            }
        }
    }
}

// ---------------------------------------------------------------------------
// K_LAYER0: fused agg0 + BN0/skip/ELU + post0 MFMA. One block per 16-node
// tile (NN = 3125*16 exactly). Waves 0-3 each aggregate 4 nodes (same math
// as before), h_act lands in LDS; after one barrier wave0 computes the h1
// MFMA tile (+ a_src1/a_dst1) and wave1 the s1 tile. hab never hits global.
// ---------------------------------------------------------------------------
__global__ __launch_bounds__(256) void k_layer0(
    const int* __restrict__ rowbeg, const int* __restrict__ deg,
    const unsigned short* __restrict__ srcidx,
    const unsigned char* __restrict__ h0f, const float* __restrict__ a_src0,
    const float* __restrict__ a_dst0, const unsigned short* __restrict__ s0b,
    const float2* __restrict__ acb0,
    const unsigned short* __restrict__ wb1,   // [32][128] bf16: w1 rows, skip1 rows
    const float* __restrict__ asrc1, const float* __restrict__ adst1,
    unsigned short* __restrict__ h1b, float* __restrict__ s1,
    float* __restrict__ a_src1, float* __restrict__ a_dst1)
{
    __shared__ unsigned short hls[16 * HSTRIDE];
    const int tid = threadIdx.x;
    const int lane = tid & 63, wave = tid >> 6;
    const int lrow = lane & 15, quad = lane >> 4;
    const int n0 = blockIdx.x * 16;

    // layer-1 weight fragments + attention vectors (waves 0/1 only)
    bf16x8 bfrag[4];
    float avec = 0.f, dvec = 0.f;
    if (wave < 2) {
        #pragma unroll
        for (int ki = 0; ki < 4; ki++)
            bfrag[ki] = *(const bf16x8*)(wb1 + (long)(wave * 16 + lrow) * 128 + ki * 32 + quad * 8);
        avec = asrc1[lrow];
        dvec = adst1[lrow];
    }

    // ---- aggregation: wave w handles nodes n0 + w*4 .. +3 ----
    const int eslot = lane >> 3;
    const int hph1 = lane & 7;
    const int c = lane * 2;
    const int hsel = lane >> 3;
    const float4 ab = *(const float4*)((const float*)acb0 + 2 * c); // (A0,B0,A1,B1)

    #pragma unroll
    for (int k = 0; k < 4; k++) {
        const int d = n0 + wave * 4 + k;
        const int beg = rowbeg[d], end = beg + deg[d];
        const float adst = a_dst0[(long)d * 8 + hph1];

        float den = 0.f;
        float2 accA = {0.f, 0.f}, accB = {0.f, 0.f};
        for (int i = beg; i < end; i += 16) {
            const int idxA = i + eslot;
            const int idxB = i + 8 + eslot;
            const bool vA = idxA < end;
            const bool vB = idxB < end;
            const int sA = vA ? (int)srcidx[idxA] : 0;
            const int sB = vB ? (int)srcidx[idxB] : 0;
            float aA = a_src0[(long)sA * 8 + hph1] + adst;
            float aB = a_src0[(long)sB * 8 + hph1] + adst;
            aA = aA > 0.f ? aA : 0.2f * aA;
            aB = aB > 0.f ? aB : 0.2f * aB;
            const float wA = vA ? __expf(aA) : 0.f;
            const float wB = vB ? __expf(aB) : 0.f;
            den += wA + wB;
            #pragma unroll
            for (int j = 0; j < 8; j++) {
                const float wjA = __shfl(wA, j * 8 + hsel);
                const int sjA = __shfl(sA, j * 8);
                const float wjB = __shfl(wB, j * 8 + hsel);
                const int sjB = __shfl(sB, j * 8);
                const unsigned int uA = *(const unsigned short*)(h0f + (long)sjA * 128 + c);
                const unsigned int uB = *(const unsigned short*)(h0f + (long)sjB * 128 + c);
                accA.x += wjA * __builtin_amdgcn_cvt_f32_fp8(uA, 0);
                accA.y += wjA * __builtin_amdgcn_cvt_f32_fp8(uA, 1);
                accB.x += wjB * __builtin_amdgcn_cvt_f32_fp8(uB, 0);
                accB.y += wjB * __builtin_amdgcn_cvt_f32_fp8(uB, 1);
            }
        }
        float2 acc = {accA.x + accB.x, accA.y + accB.y};
        den += __shfl_xor(den, 8);
        den += __shfl_xor(den, 16);
        den += __shfl_xor(den, 32);
        const float denh = __shfl(den, hsel);
        const float inv = 1.f / (denh + 1e-16f);

        // fused BN0 + skip + ELU -> LDS (bf16, same f2bf pack as before)
        const unsigned int s0u = *(const unsigned int*)(s0b + (long)d * 128 + c);
        float x0 = acc.x * inv * ab.x + ab.y + bf2f((unsigned short)s0u);
        float x1 = acc.y * inv * ab.z + ab.w + bf2f((unsigned short)(s0u >> 16));
        x0 = x0 > 0.f ? x0 : __expf(x0) - 1.f;
        x1 = x1 > 0.f ? x1 : __expf(x1) - 1.f;
        *(unsigned int*)&hls[(wave * 4 + k) * HSTRIDE + c] =
            (unsigned int)f2bf(x0) | ((unsigned int)f2bf(x1) << 16);
    }
    __syncthreads();

    // ---- layer-1 projection MFMA (waves 0/1) ----
    if (wave < 2) {
        bf16x8 afrag[4];
        #pragma unroll
        for (int ki = 0; ki < 4; ki++)
            afrag[ki] = *(const bf16x8*)&hls[lrow * HSTRIDE + ki * 32 + quad * 8];

        f32x4 acc = (f32x4){0.f, 0.f, 0.f, 0.f};
        #pragma unroll
        for (int ki = 0; ki < 4; ki++)
            acc = __builtin_amdgcn_mfma_f32_16x16x32_bf16(afrag[ki], bfrag[ki], acc, 0, 0, 0);

        // C layout: col = lane&15 (=j), row = quad*4+r (= node - n0)
        if (wave == 0) {
            #pragma unroll
            for (int r = 0; r < 4; r++) {
                const int node = n0 + quad * 4 + r;
                h1b[(long)node * 16 + lrow] = f2bf(acc[r]);
                float ps = acc[r] * avec;
                float pd = acc[r] * dvec;
                ps += __shfl_xor(ps, 1); ps += __shfl_xor(ps, 2);
                ps += __shfl_xor(ps, 4); ps += __shfl_xor(ps, 8);
                pd += __shfl_xor(pd, 1); pd += __shfl_xor(pd, 2);
                pd += __shfl_xor(pd, 4); pd += __shfl_xor(pd, 8);
                if (lrow == 0) { a_src1[node] = ps; a_dst1[node] = pd; }
            }
        } else {
            #pragma unroll
            for (int r = 0; r < 4; r++) {
                const int node = n0 + quad * 4 + r;
                s1[(long)node * 16 + lrow] = acc[r];
            }
        }
    }
}

// ---------------------------------------------------------------------------
// K5: layer-1 aggregation + BN1 + skip + ELU -> d_out, two-phase dedup + 2x
// batch interleave. 8 lanes per dst node, 2 channels per lane.
// ---------------------------------------------------------------------------
__global__ __launch_bounds__(256) void k_agg1_final(
    const int* __restrict__ rowbeg, const int* __restrict__ deg,
    const unsigned short* __restrict__ srcidx,
    const unsigned short* __restrict__ h1b, const float* __restrict__ a_src1,
    const float* __restrict__ a_dst1, const float* __restrict__ s1,
    const float2* __restrict__ acb1, float* __restrict__ out)
{
    const int gid = blockIdx.x * 256 + threadIdx.x;
    const int d = gid >> 3;                               // 8 lanes per node
    if (d >= NN) return;
    const int lane = threadIdx.x & 63;
    const int gl = lane & 7;                              // lane within group
    const int gb = lane & ~7;                             // group base lane
    const int c0 = gl * 2;
    const int beg = rowbeg[d], end = beg + deg[d];
    const float adst = a_dst1[d];

    float den = 0.f;
    float2 accA = {0.f, 0.f}, accB = {0.f, 0.f};
    for (int i = beg; i < end; i += 16) {
        const int idxA = i + gl;
        const int idxB = i + 8 + gl;
        const bool vA = idxA < end;
        const bool vB = idxB < end;
        const int sA = vA ? (int)srcidx[idxA] : 0;
        const int sB = vB ? (int)srcidx[idxB] : 0;
        float aA = a_src1[sA] + adst;
        float aB = a_src1[sB] + adst;
        aA = aA > 0.f ? aA : 0.2f * aA;
        aB = aB > 0.f ? aB : 0.2f * aB;
        const float wA = vA ? __expf(aA) : 0.f;
        const float wB = vB ? __expf(aB) : 0.f;
        den += wA + wB;
        #pragma unroll
        for (int j = 0; j < 8; j++) {
            const float wjA = __shfl(wA, gb | j);
            const int sjA = __shfl(sA, gb | j);
            const float wjB = __shfl(wB, gb | j);
            const int sjB = __shfl(sB, gb | j);
            const unsigned int uA = *(const unsigned int*)(h1b + (long)sjA * 16 + c0);
            const unsigned int uB = *(const unsigned int*)(h1b + (long)sjB * 16 + c0);
            accA.x += wjA * bf2f((unsigned short)uA);
            accA.y += wjA * bf2f((unsigned short)(uA >> 16));
            accB.x += wjB * bf2f((unsigned short)uB);
            accB.y += wjB * bf2f((unsigned short)(uB >> 16));
        }
    }
    float2 acc = {accA.x + accB.x, accA.y + accB.y};
    den += __shfl_xor(den, 1);
    den += __shfl_xor(den, 2);
    den += __shfl_xor(den, 4);
    const float inv = 1.f / (den + 1e-16f);

    const float4 ab = *(const float4*)((const float*)acb1 + 2 * c0);  // (A0,B0,A1,B1)
    float2 sv = *(const float2*)(s1 + (long)d * 16 + c0);
    float v0o = acc.x * inv * ab.x + ab.y + sv.x;
    float v1o = acc.y * inv * ab.z + ab.w + sv.y;
    v0o = v0o > 0.f ? v0o : __expf(v0o) - 1.f;
    v1o = v1o > 0.f ? v1o : __expf(v1o) - 1.f;
    *(float2*)(out + (long)d * 16 + c0) = make_float2(v0o, v1o);
}

extern "C" void kernel_launch(void* const* d_in, const int* in_sizes, int n_in,
                              void* d_out, int out_size, void* d_ws, size_t ws_size,
                              hipStream_t stream)
{
    (void)in_sizes; (void)n_in; (void)out_size; (void)ws_size;
    const float* x     = (const float*)d_in[0];
    const int*   ei    = (const int*)d_in[1];
    const float* w0    = (const float*)d_in[2];
    const float* asrc0 = (const float*)d_in[3];
    const float* adst0 = (const float*)d_in[4];
    const float* b0    = (const float*)d_in[5];
    const float* skip0 = (const float*)d_in[6];
    const float* bn0g  = (const float*)d_in[7];
    const float* bn0b  = (const float*)d_in[8];
    const float* bn0m  = (const float*)d_in[9];
    const float* bn0v  = (const float*)d_in[10];
    const float* w1    = (const float*)d_in[11];
    const float* asrc1 = (const float*)d_in[12];
    const float* adst1 = (const float*)d_in[13];
    const float* b1    = (const float*)d_in[14];
    const float* skip1 = (const float*)d_in[15];
    const float* bn1g  = (const float*)d_in[16];
    const float* bn1b  = (const float*)d_in[17];
    const float* bn1m  = (const float*)d_in[18];
    const float* bn1v  = (const float*)d_in[19];

    // workspace layout
    const long NPAIR = (long)COARSE * CAPR;                         // 1,204,224
    unsigned int* pairs = (unsigned int*)d_ws;                      // NPAIR u32
    unsigned short* wb    = (unsigned short*)(pairs + NPAIR);       // 256*128 bf16
    unsigned short* wb1   = wb + 256 * 128;                         // 32*128
    unsigned short* s0b   = wb1 + 32 * 128;                         // NN*128
    unsigned short* h1b   = s0b + (long)NN * 128;                   // NN*16
    unsigned short* srcidx= h1b + (long)NN * 16;                    // NPAIR u16
    unsigned char*  h0f   = (unsigned char*)(srcidx + NPAIR);       // NN*128 fp8
    float* a_src0 = (float*)(h0f + (long)NN * 128);                 // NN*8
    float* a_dst0 = a_src0 + (long)NN * 8;                          // NN*8
    float* s1     = a_dst0 + (long)NN * 8;                          // NN*16
    float* a_src1 = s1 + (long)NN * 16;                             // NN
    float* a_dst1 = a_src1 + NN;                                    // NN
    float2* acb0  = (float2*)(a_dst1 + NN);                         // 128 float2
    float2* acb1  = acb0 + 128;                                     // 16 float2
    int* ccur0  = (int*)(acb1 + 16);                                // COARSE (zeroed)
    int* rowbeg = ccur0 + COARSE;                                   // NN
    int* deg    = rowbeg + NN;                                      // NN

    hipMemsetAsync(ccur0, 0, (size_t)COARSE * 4, stream);

    // dispatch 1: weight cvt + BN consts  ||  partition pass A
    const int PREP_BLKS = CVT_BLKS + (EE + EPB - 1) / EPB;          // 37 + 391
    k_prep<<<PREP_BLKS, 256, 0, stream>>>(
        w0, skip0, w1, skip1,
        b0, bn0g, bn0b, bn0m, bn0v, b1, bn1g, bn1b, bn1m, bn1v,
        (unsigned int*)wb, (unsigned int*)wb1, acb0, acb1,
        ei, ccur0, pairs);

    // dispatch 2: partition pass B  ||  gemm0 (direct fp32 x)
    const int MID_BLKS = COARSE + (NN + 31) / 32;                   // 196 + 1563
    k_mid<<<MID_BLKS, 256, 0, stream>>>(
        pairs, ccur0, srcidx, rowbeg, deg,
        x, wb, asrc0, adst0, h0f, s0b, a_src0, a_dst0);

    // dispatch 3: layer-0 aggregation + BN/skip/ELU + layer-1 projection
    k_layer0<<<NN / 16, 256, 0, stream>>>(rowbeg, deg, srcidx, h0f,
                                          a_src0, a_dst0, s0b, acb0,
                                          wb1, asrc1, adst1,
                                          h1b, s1, a_src1, a_dst1);

    // dispatch 4: layer-1 aggregation + epilogue
    k_agg1_final<<<(NN * 8 + 255) / 256, 256, 0, stream>>>(rowbeg, deg, srcidx, h1b,
                                                           a_src1, a_dst1, s1,
                                                           acb1, (float*)d_out);
}

// Round 17
// 203.558 us; speedup vs baseline: 1.1045x; 1.1045x over previous
//
#include <hip/hip_runtime.h>
#include <hip/hip_bf16.h>

#define NN 50000
#define EE 800000
#define INDIM 128
#define HIDC 16
#define NHEAD 8
#define COARSE 196          // ceil(NN/256)
#define EPB 2048            // edges per block in partition pass A
#define CAPR 6144           // fixed region stride per coarse bin (avg cnt ~4082)
#define CAPB 8192           // partB LDS stage capacity (>= CAPR)
#define CVT_BLKS 37         // ceil((256*128/4 + 32*128/4 + 144)/256)

typedef __attribute__((ext_vector_type(8))) short bf16x8;
typedef __attribute__((ext_vector_type(4))) float f32x4;

__device__ __forceinline__ float bf2f(unsigned short u) {
    union { float f; unsigned int i; } v; v.i = ((unsigned int)u) << 16; return v.f;
}
__device__ __forceinline__ unsigned short f2bf(float f) {
    union { float f; unsigned int i; } v; v.f = f;
    unsigned int r = v.i + 0x7FFFu + ((v.i >> 16) & 1u);
    return (unsigned short)(r >> 16);
}

// ---------------------------------------------------------------------------
// K_PREP: blocks [0, CVT_BLKS): weight bf16 conversion + BN constants.
//         blocks [CVT_BLKS, ...): partition pass A (independent of cvt).
// ---------------------------------------------------------------------------
__global__ __launch_bounds__(256) void k_prep(
    const float* __restrict__ w0, const float* __restrict__ skip0,
    const float* __restrict__ w1, const float* __restrict__ skip1,
    const float* __restrict__ b0, const float* __restrict__ g0,
    const float* __restrict__ bb0, const float* __restrict__ m0,
    const float* __restrict__ v0,
    const float* __restrict__ b1, const float* __restrict__ g1,
    const float* __restrict__ bb1, const float* __restrict__ m1,
    const float* __restrict__ v1,
    unsigned int* __restrict__ wb2, unsigned int* __restrict__ wb1_2,
    float2* __restrict__ acb0, float2* __restrict__ acb1,
    const int* __restrict__ ei, int* __restrict__ ccur0,
    unsigned int* __restrict__ pairs)
{
    if (blockIdx.x < CVT_BLKS) {
        const long NW = 256 * 128 / 4;           // w0|skip0 float4 blocks
        const long NW1 = 32 * 128 / 4;           // w1|skip1
        long i = (long)blockIdx.x * 256 + threadIdx.x;
        if (i < NW) {
            const float4* src = (i < 128 * 128 / 4) ? ((const float4*)w0 + i)
                                                    : ((const float4*)skip0 + (i - 128 * 128 / 4));
            float4 v = *src;
            wb2[i * 2]     = (unsigned int)f2bf(v.x) | ((unsigned int)f2bf(v.y) << 16);
            wb2[i * 2 + 1] = (unsigned int)f2bf(v.z) | ((unsigned int)f2bf(v.w) << 16);
        } else if (i < NW + NW1) {
            long j = i - NW;
            const float4* src = (j < 16 * 128 / 4) ? ((const float4*)w1 + j)
                                                   : ((const float4*)skip1 + (j - 16 * 128 / 4));
            float4 v = *src;
            wb1_2[j * 2]     = (unsigned int)f2bf(v.x) | ((unsigned int)f2bf(v.y) << 16);
            wb1_2[j * 2 + 1] = (unsigned int)f2bf(v.z) | ((unsigned int)f2bf(v.w) << 16);
        } else if (i < NW + NW1 + 128) {
            int c = (int)(i - NW - NW1);
            float A = g0[c] * rsqrtf(v0[c] + 1e-5f);
            acb0[c] = make_float2(A, (b0[c] - m0[c]) * A + bb0[c]);
        } else if (i < NW + NW1 + 128 + 16) {
            int c = (int)(i - NW - NW1 - 128);
            float A = g1[c] * rsqrtf(v1[c] + 1e-5f);
            acb1[c] = make_float2(A, (b1[c] - m1[c]) * A + bb1[c]);
        }
        return;
    }

    // ---- partition pass A ----
    __shared__ int bcnt[256];
    __shared__ int lofs[256];
    __shared__ int gofs[256];
    __shared__ unsigned int stage[EPB];
    __shared__ int gpos[EPB];
    const int t = threadIdx.x;
    const int e0 = (blockIdx.x - CVT_BLKS) * EPB;

    bcnt[t] = 0;
    __syncthreads();

    int mybin[8], myrank[8];
    unsigned int mypair[8];
    #pragma unroll
    for (int k = 0; k < 8; k++) {
        int e = e0 + k * 256 + t;
        mybin[k] = -1;
        if (e < EE) {
            int s = ei[e], d = ei[EE + e];
            int b = d >> 8;
            myrank[k] = atomicAdd(&bcnt[b], 1);
            mybin[k] = b;
            mypair[k] = ((unsigned)d << 16) | (unsigned)s;
        }
    }
    __syncthreads();

    int v = bcnt[t];
    lofs[t] = v;
    __syncthreads();
    for (int off = 1; off < 256; off <<= 1) {
        int u = (t >= off) ? lofs[t - off] : 0;
        __syncthreads();
        lofs[t] += u;
        __syncthreads();
    }
    if (t < COARSE && v > 0)
        gofs[t] = t * CAPR + atomicAdd(&ccur0[t], v);
    __syncthreads();

    #pragma unroll
    for (int k = 0; k < 8; k++) {
        int b = mybin[k];
        if (b >= 0) {
            int slot = (lofs[b] - bcnt[b]) + myrank[k];
            stage[slot] = mypair[k];
            gpos[slot]  = gofs[b] + myrank[k];
        }
    }
    __syncthreads();

    const int total = lofs[255];
    for (int i = t; i < total; i += 256)
        pairs[gpos[i]] = stage[i];
}

// ---------------------------------------------------------------------------
// K_MID: blocks [0, COARSE): partition pass B (LDS counting-sort by dst).
//        blocks [COARSE, ...): gemm0 (needs only wb from k_prep).
// ---------------------------------------------------------------------------
__global__ __launch_bounds__(256) void k_mid(
    const unsigned int* __restrict__ pairs, const int* __restrict__ ccur0,
    unsigned short* __restrict__ srcidx, int* __restrict__ rowbeg,
    int* __restrict__ deg,
    const float* __restrict__ x, const unsigned short* __restrict__ wb,
    const float* __restrict__ asrc0, const float* __restrict__ adst0,
    unsigned char* __restrict__ h0f, unsigned short* __restrict__ s0b,
    float* __restrict__ a_src0, float* __restrict__ a_dst0)
{
    __shared__ int fcnt[256], fofs[256], fcur[256];
    __shared__ unsigned short stage[CAPB];

    if (blockIdx.x < COARSE) {
        const int b = blockIdx.x, t = threadIdx.x;
        const int beg = b * CAPR;
        int cnt = ccur0[b];
        if (cnt > CAPR) cnt = CAPR;   // safety clamp

        fcnt[t] = 0;
        __syncthreads();
        for (int i = t; i < cnt; i += 256) {
            unsigned int d = pairs[beg + i] >> 16;
            atomicAdd(&fcnt[d & 255], 1);
        }
        __syncthreads();

        int v = fcnt[t];
        fofs[t] = v;
        __syncthreads();
        for (int off = 1; off < 256; off <<= 1) {
            int u = (t >= off) ? fofs[t - off] : 0;
            __syncthreads();
            fofs[t] += u;
            __syncthreads();
        }
        int ex = fofs[t] - v;
        int node = b * 256 + t;
        if (node < NN) { rowbeg[node] = beg + ex; deg[node] = v; }
        fcur[t] = ex;
        __syncthreads();

        for (int i = t; i < cnt; i += 256) {
            unsigned int p = pairs[beg + i];
            unsigned int d = p >> 16;
            int slot = atomicAdd(&fcur[d & 255], 1);
            stage[slot] = (unsigned short)(p & 0xFFFFu);
        }
        __syncthreads();
        for (int i = t; i < cnt; i += 256)
            srcidx[beg + i] = stage[i];
        return;
    }

    // ---- gemm0 ----
    const int bid = blockIdx.x - COARSE;
    const int wave = threadIdx.x >> 6;
    const int lane = threadIdx.x & 63;
    const int lrow = lane & 15;
    const int quad = lane >> 4;
    const int rowbase = bid * 32;

    // A fragments for 2 row-subtiles, from fp32 x, converted in-register
    bf16x8 afrag[2][4];
    #pragma unroll
    for (int sub = 0; sub < 2; sub++) {
        const int row = min(rowbase + sub * 16 + lrow, NN - 1);
        const float* xr = x + (long)row * 128;
        #pragma unroll
        for (int ki = 0; ki < 4; ki++) {
            float4 a = *(const float4*)(xr + ki * 32 + quad * 8);
            float4 b = *(const float4*)(xr + ki * 32 + quad * 8 + 4);
            bf16x8 f;
            f[0] = (short)f2bf(a.x); f[1] = (short)f2bf(a.y);
            f[2] = (short)f2bf(a.z); f[3] = (short)f2bf(a.w);
            f[4] = (short)f2bf(b.x); f[5] = (short)f2bf(b.y);
            f[6] = (short)f2bf(b.z); f[7] = (short)f2bf(b.w);
            afrag[sub][ki] = f;
        }
    }

    #pragma unroll
    for (int t = 0; t < 4; t++) {
        const int jg = wave * 64 + t * 16 + lrow;
        bf16x8 bfrag[4];
        #pragma unroll
        for (int ki = 0; ki < 4; ki++)
            bfrag[ki] = *(const bf16x8*)(wb + (long)jg * 128 + ki * 32 + quad * 8);
        float4 asv = {0.f, 0.f, 0.f, 0.f}, adv = {0.f, 0.f, 0.f, 0.f};
        if (wave < 2) {
            const int cb = wave * 64 + t * 16 + quad * 4;
            asv = *(const float4*)(asrc0 + cb);
            adv = *(const float4*)(adst0 + cb);
        }
        #pragma unroll
        for (int sub = 0; sub < 2; sub++) {
            f32x4 acc = (f32x4){0.f, 0.f, 0.f, 0.f};
            // swapped operands: D^T -> col(lane&15)=node, row(quad*4+r)=channel
            #pragma unroll
            for (int ki = 0; ki < 4; ki++)
                acc = __builtin_amdgcn_mfma_f32_16x16x32_bf16(bfrag[ki], afrag[sub][ki], acc, 0, 0, 0);

            const int node = rowbase + sub * 16 + lrow;
            if (node < NN) {
                if (wave < 2) {
                    const int cb = wave * 64 + t * 16 + quad * 4;
                    unsigned int u = __builtin_amdgcn_cvt_pk_fp8_f32(acc[0], acc[1], 0u, 0);
                    u = __builtin_amdgcn_cvt_pk_fp8_f32(acc[2], acc[3], u, 1);
                    *(unsigned int*)(h0f + (long)node * 128 + cb) = u;
                    float ps = acc[0] * asv.x + acc[1] * asv.y + acc[2] * asv.z + acc[3] * asv.w;
                    float pd = acc[0] * adv.x + acc[1] * adv.y + acc[2] * adv.z + acc[3] * adv.w;
                    ps += __shfl_xor(ps, 16); ps += __shfl_xor(ps, 32);
                    pd += __shfl_xor(pd, 16); pd += __shfl_xor(pd, 32);
                    if (quad == 0) {
                        const int h = wave * 4 + t;
                        a_src0[(long)node * 8 + h] = ps;
                        a_dst0[(long)node * 8 + h] = pd;
                    }
                } else {
                    const int cb = (wave - 2) * 64 + t * 16 + quad * 4;
                    uint2 u;
                    u.x = (unsigned int)f2bf(acc[0]) | ((unsigned int)f2bf(acc[1]) << 16);
                    u.y = (unsigned int)f2bf(acc[2]) | ((unsigned int)f2bf(acc[3]) << 16);
                    *(uint2*)(s0b + (long)node * 128 + cb) = u;
                }
            }
        }
    }
}

// ---------------------------------------------------------------------------
// K3: layer-0 aggregation + FUSED BN0/skip/ELU epilogue -> hab (bf16 h_act).
// fp8 h0 table; two-phase dedup + 2x batch interleave; ONE WAVE PER NODE
// (50000 waves — TLP is what hides gather latency; R16 proved fusing the
// projection here at 1/4 the waves regresses).
// ---------------------------------------------------------------------------
__global__ __launch_bounds__(256) void k_agg0(
    const int* __restrict__ rowbeg, const int* __restrict__ deg,
    const unsigned short* __restrict__ srcidx,
    const unsigned char* __restrict__ h0f, const float* __restrict__ a_src0,
    const float* __restrict__ a_dst0, const unsigned short* __restrict__ s0b,
    const float2* __restrict__ acb0, unsigned int* __restrict__ hab2)
{
    const int d = (blockIdx.x * 256 + threadIdx.x) >> 6;  // one wave per node
    if (d >= NN) return;
    const int lane = threadIdx.x & 63;
    const int beg = rowbeg[d], end = beg + deg[d];
    const int eslot = lane >> 3;                          // phase-1 edge slot
    const int hph1 = lane & 7;                            // phase-1 head
    const int c = lane * 2;                               // phase-2 channels
    const int hsel = lane >> 3;                           // head for channels c
    const float adst = a_dst0[(long)d * 8 + hph1];

    float den = 0.f;
    float2 accA = {0.f, 0.f}, accB = {0.f, 0.f};
    for (int i = beg; i < end; i += 16) {
        const int idxA = i + eslot;
        const int idxB = i + 8 + eslot;
        const bool vA = idxA < end;
        const bool vB = idxB < end;
        const int sA = vA ? (int)srcidx[idxA] : 0;
        const int sB = vB ? (int)srcidx[idxB] : 0;
        float aA = a_src0[(long)sA * 8 + hph1] + adst;
        float aB = a_src0[(long)sB * 8 + hph1] + adst;
        aA = aA > 0.f ? aA : 0.2f * aA;
        aB = aB > 0.f ? aB : 0.2f * aB;
        const float wA = vA ? __expf(aA) : 0.f;
        const float wB = vB ? __expf(aB) : 0.f;
        den += wA + wB;
        #pragma unroll
        for (int j = 0; j < 8; j++) {
            const float wjA = __shfl(wA, j * 8 + hsel);
            const int sjA = __shfl(sA, j * 8);
            const float wjB = __shfl(wB, j * 8 + hsel);
            const int sjB = __shfl(sB, j * 8);
            const unsigned int uA = *(const unsigned short*)(h0f + (long)sjA * 128 + c);
            const unsigned int uB = *(const unsigned short*)(h0f + (long)sjB * 128 + c);
            accA.x += wjA * __builtin_amdgcn_cvt_f32_fp8(uA, 0);
            accA.y += wjA * __builtin_amdgcn_cvt_f32_fp8(uA, 1);
            accB.x += wjB * __builtin_amdgcn_cvt_f32_fp8(uB, 0);
            accB.y += wjB * __builtin_amdgcn_cvt_f32_fp8(uB, 1);
        }
    }
    float2 acc = {accA.x + accB.x, accA.y + accB.y};
    den += __shfl_xor(den, 8);
    den += __shfl_xor(den, 16);
    den += __shfl_xor(den, 32);
    const float denh = __shfl(den, hsel);
    const float inv = 1.f / (denh + 1e-16f);

    // fused BN0 + skip + ELU
    const float4 ab = *(const float4*)((const float*)acb0 + 2 * c); // (A0,B0,A1,B1)
    const unsigned int s0u = *(const unsigned int*)(s0b + (long)d * 128 + c);
    float x0 = acc.x * inv * ab.x + ab.y + bf2f((unsigned short)s0u);
    float x1 = acc.y * inv * ab.z + ab.w + bf2f((unsigned short)(s0u >> 16));
    x0 = x0 > 0.f ? x0 : __expf(x0) - 1.f;
    x1 = x1 > 0.f ? x1 : __expf(x1) - 1.f;
    hab2[(long)d * 64 + lane] =
        (unsigned int)f2bf(x0) | ((unsigned int)f2bf(x1) << 16);
}

// ---------------------------------------------------------------------------
// K4: slim post0: afrag = direct bf16x8 loads of h_act, two 16x16x32 MFMA
// tiles per 16 nodes -> h1b/s1 + a_src1/a_dst1.
// ---------------------------------------------------------------------------
__global__ __launch_bounds__(256) void k_post0(
    const unsigned short* __restrict__ hab,
    const unsigned short* __restrict__ wb1,     // [32][128] bf16: w1 rows, skip1 rows
    const float* __restrict__ asrc1, const float* __restrict__ adst1,
    unsigned short* __restrict__ h1b, float* __restrict__ s1,
    float* __restrict__ a_src1, float* __restrict__ a_dst1)
{
    const int tid = threadIdx.x;
    const int lane = tid & 63, wave = tid >> 6;
    const int lrow = lane & 15, quad = lane >> 4;

    bf16x8 bfrag[2][4];
    #pragma unroll
    for (int t = 0; t < 2; t++)
        #pragma unroll
        for (int ki = 0; ki < 4; ki++)
            bfrag[t][ki] = *(const bf16x8*)(wb1 + (long)(t * 16 + lrow) * 128 + ki * 32 + quad * 8);
    const float avec = asrc1[lrow];
    const float dvec = adst1[lrow];

    const int tile = blockIdx.x * 4 + wave;           // 16 nodes per tile
    if (tile * 16 >= NN) return;
    const int n0 = tile * 16;
    const long arow = (long)(n0 + lrow) * 128;

    bf16x8 afrag[4];
    #pragma unroll
    for (int ki = 0; ki < 4; ki++)
        afrag[ki] = *(const bf16x8*)(hab + arow + ki * 32 + quad * 8);

    f32x4 acc0 = (f32x4){0.f, 0.f, 0.f, 0.f};   // h1 tile
    f32x4 acc1 = (f32x4){0.f, 0.f, 0.f, 0.f};   // s1 tile
    #pragma unroll
    for (int ki = 0; ki < 4; ki++) {
        acc0 = __builtin_amdgcn_mfma_f32_16x16x32_bf16(afrag[ki], bfrag[0][ki], acc0, 0, 0, 0);
        acc1 = __builtin_amdgcn_mfma_f32_16x16x32_bf16(afrag[ki], bfrag[1][ki], acc1, 0, 0, 0);
    }

    // C layout: col = lane&15 (=j), row = quad*4+r (= node - n0)
    #pragma unroll
    for (int r = 0; r < 4; r++) {
        const int node = n0 + quad * 4 + r;
        h1b[(long)node * 16 + lrow] = f2bf(acc0[r]);
        s1[(long)node * 16 + lrow] = acc1[r];
        float ps = acc0[r] * avec;
        float pd = acc0[r] * dvec;
        ps += __shfl_xor(ps, 1); ps += __shfl_xor(ps, 2);
        ps += __shfl_xor(ps, 4); ps += __shfl_xor(ps, 8);
        pd += __shfl_xor(pd, 1); pd += __shfl_xor(pd, 2);
        pd += __shfl_xor(pd, 4); pd += __shfl_xor(pd, 8);
        if (lrow == 0) { a_src1[node] = ps; a_dst1[node] = pd; }
    }
}

// ---------------------------------------------------------------------------
// K5: layer-1 aggregation + BN1 + skip + ELU -> d_out, two-phase dedup + 2x
// batch interleave. 8 lanes per dst node, 2 channels per lane.
// ---------------------------------------------------------------------------
__global__ __launch_bounds__(256) void k_agg1_final(
    const int* __restrict__ rowbeg, const int* __restrict__ deg,
    const unsigned short* __restrict__ srcidx,
    const unsigned short* __restrict__ h1b, const float* __restrict__ a_src1,
    const float* __restrict__ a_dst1, const float* __restrict__ s1,
    const float2* __restrict__ acb1, float* __restrict__ out)
{
    const int gid = blockIdx.x * 256 + threadIdx.x;
    const int d = gid >> 3;                               // 8 lanes per node
    if (d >= NN) return;
    const int lane = threadIdx.x & 63;
    const int gl = lane & 7;                              // lane within group
    const int gb = lane & ~7;                             // group base lane
    const int c0 = gl * 2;
    const int beg = rowbeg[d], end = beg + deg[d];
    const float adst = a_dst1[d];

    float den = 0.f;
    float2 accA = {0.f, 0.f}, accB = {0.f, 0.f};
    for (int i = beg; i < end; i += 16) {
        const int idxA = i + gl;
        const int idxB = i + 8 + gl;
        const bool vA = idxA < end;
        const bool vB = idxB < end;
        const int sA = vA ? (int)srcidx[idxA] : 0;
        const int sB = vB ? (int)srcidx[idxB] : 0;
        float aA = a_src1[sA] + adst;
        float aB = a_src1[sB] + adst;
        aA = aA > 0.f ? aA : 0.2f * aA;
        aB = aB > 0.f ? aB : 0.2f * aB;
        const float wA = vA ? __expf(aA) : 0.f;
        const float wB = vB ? __expf(aB) : 0.f;
        den += wA + wB;
        #pragma unroll
        for (int j = 0; j < 8; j++) {
            const float wjA = __shfl(wA, gb | j);
            const int sjA = __shfl(sA, gb | j);
            const float wjB = __shfl(wB, gb | j);
            const int sjB = __shfl(sB, gb | j);
            const unsigned int uA = *(const unsigned int*)(h1b + (long)sjA * 16 + c0);
            const unsigned int uB = *(const unsigned int*)(h1b + (long)sjB * 16 + c0);
            accA.x += wjA * bf2f((unsigned short)uA);
            accA.y += wjA * bf2f((unsigned short)(uA >> 16));
            accB.x += wjB * bf2f((unsigned short)uB);
            accB.y += wjB * bf2f((unsigned short)(uB >> 16));
        }
    }
    float2 acc = {accA.x + accB.x, accA.y + accB.y};
    den += __shfl_xor(den, 1);
    den += __shfl_xor(den, 2);
    den += __shfl_xor(den, 4);
    const float inv = 1.f / (den + 1e-16f);

    const float4 ab = *(const float4*)((const float*)acb1 + 2 * c0);  // (A0,B0,A1,B1)
    float2 sv = *(const float2*)(s1 + (long)d * 16 + c0);
    float v0o = acc.x * inv * ab.x + ab.y + sv.x;
    float v1o = acc.y * inv * ab.z + ab.w + sv.y;
    v0o = v0o > 0.f ? v0o : __expf(v0o) - 1.f;
    v1o = v1o > 0.f ? v1o : __expf(v1o) - 1.f;
    *(float2*)(out + (long)d * 16 + c0) = make_float2(v0o, v1o);
}

extern "C" void kernel_launch(void* const* d_in, const int* in_sizes, int n_in,
                              void* d_out, int out_size, void* d_ws, size_t ws_size,
                              hipStream_t stream)
{
    (void)in_sizes; (void)n_in; (void)out_size; (void)ws_size;
    const float* x     = (const float*)d_in[0];
    const int*   ei    = (const int*)d_in[1];
    const float* w0    = (const float*)d_in[2];
    const float* asrc0 = (const float*)d_in[3];
    const float* adst0 = (const float*)d_in[4];
    const float* b0    = (const float*)d_in[5];
    const float* skip0 = (const float*)d_in[6];
    const float* bn0g  = (const float*)d_in[7];
    const float* bn0b  = (const float*)d_in[8];
    const float* bn0m  = (const float*)d_in[9];
    const float* bn0v  = (const float*)d_in[10];
    const float* w1    = (const float*)d_in[11];
    const float* asrc1 = (const float*)d_in[12];
    const float* adst1 = (const float*)d_in[13];
    const float* b1    = (const float*)d_in[14];
    const float* skip1 = (const float*)d_in[15];
    const float* bn1g  = (const float*)d_in[16];
    const float* bn1b  = (const float*)d_in[17];
    const float* bn1m  = (const float*)d_in[18];
    const float* bn1v  = (const float*)d_in[19];

    // workspace layout
    const long NPAIR = (long)COARSE * CAPR;                         // 1,204,224
    unsigned int* pairs = (unsigned int*)d_ws;                      // NPAIR u32
    unsigned short* wb    = (unsigned short*)(pairs + NPAIR);       // 256*128 bf16
    unsigned short* wb1   = wb + 256 * 128;                         // 32*128
    unsigned short* s0b   = wb1 + 32 * 128;                         // NN*128
    unsigned short* hab   = s0b + (long)NN * 128;                   // NN*128 (bf16 h_act)
    unsigned short* h1b   = hab + (long)NN * 128;                   // NN*16
    unsigned short* srcidx= h1b + (long)NN * 16;                    // NPAIR u16
    unsigned char*  h0f   = (unsigned char*)(srcidx + NPAIR);       // NN*128 fp8
    float* a_src0 = (float*)(h0f + (long)NN * 128);                 // NN*8
    float* a_dst0 = a_src0 + (long)NN * 8;                          // NN*8
    float* s1     = a_dst0 + (long)NN * 8;                          // NN*16
    float* a_src1 = s1 + (long)NN * 16;                             // NN
    float* a_dst1 = a_src1 + NN;                                    // NN
    float2* acb0  = (float2*)(a_dst1 + NN);                         // 128 float2
    float2* acb1  = acb0 + 128;                                     // 16 float2
    int* ccur0  = (int*)(acb1 + 16);                                // COARSE (zeroed)
    int* rowbeg = ccur0 + COARSE;                                   // NN
    int* deg    = rowbeg + NN;                                      // NN

    hipMemsetAsync(ccur0, 0, (size_t)COARSE * 4, stream);

    // dispatch 1: weight cvt + BN consts  ||  partition pass A
    const int PREP_BLKS = CVT_BLKS + (EE + EPB - 1) / EPB;          // 37 + 391
    k_prep<<<PREP_BLKS, 256, 0, stream>>>(
        w0, skip0, w1, skip1,
        b0, bn0g, bn0b, bn0m, bn0v, b1, bn1g, bn1b, bn1m, bn1v,
        (unsigned int*)wb, (unsigned int*)wb1, acb0, acb1,
        ei, ccur0, pairs);

    // dispatch 2: partition pass B  ||  gemm0 (direct fp32 x)
    const int MID_BLKS = COARSE + (NN + 31) / 32;                   // 196 + 1563
    k_mid<<<MID_BLKS, 256, 0, stream>>>(
        pairs, ccur0, srcidx, rowbeg, deg,
        x, wb, asrc0, adst0, h0f, s0b, a_src0, a_dst0);

    // layer 0 aggregation + fused BN/skip/ELU
    k_agg0<<<(NN * 64 + 255) / 256, 256, 0, stream>>>(rowbeg, deg, srcidx, h0f,
                                                      a_src0, a_dst0, s0b, acb0,
                                                      (unsigned int*)hab);
    k_post0<<<(NN / 16 + 3) / 4, 256, 0, stream>>>(hab, wb1, asrc1, adst1,
                                                   h1b, s1, a_src1, a_dst1);
    // layer 1 + epilogue
    k_agg1_final<<<(NN * 8 + 255) / 256, 256, 0, stream>>>(rowbeg, deg, srcidx, h1b,
                                                           a_src1, a_dst1, s1,
                                                           acb1, (float*)d_out);
}